// Round 1
// baseline (9014.875 us; speedup 1.0000x reference)
//
#include <hip/hip_runtime.h>

#define R_STAGES 8
#define H_HEADS  8
#define K_CODES  4096
#define C_DIM    128
#define N_TOK    4096      // B*S = 2*2048
#define FEAT     1024      // H*C

#define TN 64              // tokens per block in stage kernel
#define TK 64              // codes per LDS tile

// ---------------------------------------------------------------------------
// ws layout (bytes):
//   t   : float [H][N][C]     @ 0            (16,777,216 B)
//   ps  : float [N]           @ 16,777,216   (16,384 B)
//   cbn : double [R][H][K]    @ 16,793,600   (2,097,152 B)
// total: 18,890,752 B
// ---------------------------------------------------------------------------

// Permute x (per head: [2][64] -> [64][2] interleave), compute prescale = ||xp||,
// write t0 = xp / prescale in (H, N, C) layout.
__global__ void kc_prep(const float* __restrict__ x, float* __restrict__ t,
                        float* __restrict__ ps) {
    int n = blockIdx.x;
    const float* xr = x + (size_t)n * FEAT;

    double ss = 0.0;
    for (int i = threadIdx.x; i < FEAT; i += 256) {
        float v = xr[i];
        ss += (double)v * (double)v;
    }
    for (int off = 32; off > 0; off >>= 1) ss += __shfl_down(ss, off);

    __shared__ double sred[4];
    __shared__ float s_p;
    int wid = threadIdx.x >> 6, lane = threadIdx.x & 63;
    if (lane == 0) sred[wid] = ss;
    __syncthreads();
    if (threadIdx.x == 0) {
        double tot = sred[0] + sred[1] + sred[2] + sred[3];
        float p = (float)sqrt(tot);
        ps[n] = p;
        s_p = p;
    }
    __syncthreads();
    float p = s_p;

    for (int i = threadIdx.x; i < FEAT; i += 256) {
        int c = i & 127;
        // xp[h*128 + c] = x[h*128 + (c&1)*64 + (c>>1)]
        float v = xr[(i & ~127) + ((c & 1) << 6) + (c >> 1)];
        size_t o = ((size_t)(i >> 7) * N_TOK + n) * C_DIM + c;
        t[o] = v / p;
    }
}

// cbn[r,h,k] = sum_c cb^2 in fp64. One wave per codebook row.
__global__ void kc_cbn(const float* __restrict__ cb, double* __restrict__ cbn) {
    int w = (blockIdx.x << 2) + (threadIdx.x >> 6);   // row id, 0..R*H*K-1
    int lane = threadIdx.x & 63;
    const float* row = cb + (size_t)w * C_DIM;
    float a = row[lane], b = row[lane + 64];
    double s = (double)a * a + (double)b * b;
    for (int off = 32; off > 0; off >>= 1) s += __shfl_down(s, off);
    if (lane == 0) cbn[w] = s;
}

// One residual stage: per (h, token) argmin_k (cbn[k] - 2*dot(t, cb_k)) in fp64,
// then t -= cb[argmin]. Block = 64 tokens x all K for one head.
__global__ __launch_bounds__(256, 2)
void kc_stage(const float* __restrict__ cb, const double* __restrict__ cbn,
              float* __restrict__ t, int r) {
    extern __shared__ char smem[];
    float*  tl    = (float*)(smem);                 // [TN][129]  33,024 B
    float*  cl    = (float*)(smem + 33024);         // [TK][129]  33,024 B
    double* bestD = (double*)(smem + 66048);        // [TN][17]    8,704 B
    int*    bestI = (int*)(smem + 74752);           // [TN][17]    4,352 B
    int*    winner = (int*)(smem + 79104);          // [TN]          256 B

    int h  = blockIdx.x >> 6;             // N/TN = 64 token tiles per head
    int n0 = (blockIdx.x & 63) * TN;
    const float*  cbh  = cb  + ((size_t)(r * H_HEADS + h) * K_CODES) * C_DIM;
    const double* cbnh = cbn + (size_t)(r * H_HEADS + h) * K_CODES;
    float* th = t + ((size_t)h * N_TOK + n0) * C_DIM;

    // stage t tile
    for (int i = threadIdx.x; i < TN * C_DIM; i += 256) {
        int tok = i >> 7, c = i & 127;
        tl[tok * 129 + c] = th[(size_t)tok * C_DIM + c];
    }

    int tg = threadIdx.x & 15;   // token group: tokens tg*4 + 0..3
    int kg = threadIdx.x >> 4;   // code group:  k = k0 + kg*4 + 0..3

    double bd0 = 1e300, bd1 = 1e300, bd2 = 1e300, bd3 = 1e300;
    int    bi0 = 0, bi1 = 0, bi2 = 0, bi3 = 0;

    const float* tb = tl + (tg * 4) * 129;

    for (int k0 = 0; k0 < K_CODES; k0 += TK) {
        __syncthreads();
        for (int i = threadIdx.x; i < TK * C_DIM; i += 256) {
            int kk = i >> 7, c = i & 127;
            cl[kk * 129 + c] = cbh[(size_t)(k0 + kk) * C_DIM + c];
        }
        __syncthreads();

        double acc[4][4] = {};
        const float* cbq = cl + (kg * 4) * 129;
        #pragma unroll 8
        for (int c = 0; c < C_DIM; ++c) {
            double tv0 = (double)tb[c];
            double tv1 = (double)tb[129 + c];
            double tv2 = (double)tb[258 + c];
            double tv3 = (double)tb[387 + c];
            double cv0 = (double)cbq[c];
            double cv1 = (double)cbq[129 + c];
            double cv2 = (double)cbq[258 + c];
            double cv3 = (double)cbq[387 + c];
            acc[0][0] = fma(tv0, cv0, acc[0][0]);
            acc[0][1] = fma(tv0, cv1, acc[0][1]);
            acc[0][2] = fma(tv0, cv2, acc[0][2]);
            acc[0][3] = fma(tv0, cv3, acc[0][3]);
            acc[1][0] = fma(tv1, cv0, acc[1][0]);
            acc[1][1] = fma(tv1, cv1, acc[1][1]);
            acc[1][2] = fma(tv1, cv2, acc[1][2]);
            acc[1][3] = fma(tv1, cv3, acc[1][3]);
            acc[2][0] = fma(tv2, cv0, acc[2][0]);
            acc[2][1] = fma(tv2, cv1, acc[2][1]);
            acc[2][2] = fma(tv2, cv2, acc[2][2]);
            acc[2][3] = fma(tv2, cv3, acc[2][3]);
            acc[3][0] = fma(tv3, cv0, acc[3][0]);
            acc[3][1] = fma(tv3, cv1, acc[3][1]);
            acc[3][2] = fma(tv3, cv2, acc[3][2]);
            acc[3][3] = fma(tv3, cv3, acc[3][3]);
        }

        #pragma unroll
        for (int b2 = 0; b2 < 4; ++b2) {
            int kidx = k0 + kg * 4 + b2;
            double cn = cbnh[kidx];
            double d0 = cn - 2.0 * acc[0][b2];
            double d1 = cn - 2.0 * acc[1][b2];
            double d2 = cn - 2.0 * acc[2][b2];
            double d3 = cn - 2.0 * acc[3][b2];
            if (d0 < bd0 || (d0 == bd0 && kidx < bi0)) { bd0 = d0; bi0 = kidx; }
            if (d1 < bd1 || (d1 == bd1 && kidx < bi1)) { bd1 = d1; bi1 = kidx; }
            if (d2 < bd2 || (d2 == bd2 && kidx < bi2)) { bd2 = d2; bi2 = kidx; }
            if (d3 < bd3 || (d3 == bd3 && kidx < bi3)) { bd3 = d3; bi3 = kidx; }
        }
    }

    __syncthreads();
    {
        int tok = tg * 4;
        bestD[(tok + 0) * 17 + kg] = bd0;  bestI[(tok + 0) * 17 + kg] = bi0;
        bestD[(tok + 1) * 17 + kg] = bd1;  bestI[(tok + 1) * 17 + kg] = bi1;
        bestD[(tok + 2) * 17 + kg] = bd2;  bestI[(tok + 2) * 17 + kg] = bi2;
        bestD[(tok + 3) * 17 + kg] = bd3;  bestI[(tok + 3) * 17 + kg] = bi3;
    }
    __syncthreads();
    if (threadIdx.x < TN) {
        int tok = threadIdx.x;
        double bD = bestD[tok * 17];
        int    bI = bestI[tok * 17];
        for (int j = 1; j < 16; ++j) {
            double d = bestD[tok * 17 + j];
            int    i = bestI[tok * 17 + j];
            if (d < bD || (d == bD && i < bI)) { bD = d; bI = i; }
        }
        winner[tok] = bI;
    }
    __syncthreads();

    // t -= cb[winner] (fp32, matching reference residual update)
    for (int i = threadIdx.x; i < TN * C_DIM; i += 256) {
        int tok = i >> 7, c = i & 127;
        float q = cbh[(size_t)winner[tok] * C_DIM + c];
        th[(size_t)tok * C_DIM + c] = tl[tok * 129 + c] - q;
    }
}

// out[n, h*128+c] = (t0 - t_final) * prescale, t0 recomputed exactly as in prep.
__global__ void kc_out(const float* __restrict__ x, const float* __restrict__ t,
                       const float* __restrict__ ps, float* __restrict__ out) {
    int n = blockIdx.x;
    float p = ps[n];
    const float* xr = x + (size_t)n * FEAT;
    for (int i = threadIdx.x; i < FEAT; i += 256) {
        int c = i & 127;
        float v = xr[(i & ~127) + ((c & 1) << 6) + (c >> 1)];
        float t0 = v / p;
        float tf = t[((size_t)(i >> 7) * N_TOK + n) * C_DIM + c];
        out[(size_t)n * FEAT + i] = (t0 - tf) * p;
    }
}

extern "C" void kernel_launch(void* const* d_in, const int* in_sizes, int n_in,
                              void* d_out, int out_size, void* d_ws, size_t ws_size,
                              hipStream_t stream) {
    const float* x  = (const float*)d_in[0];
    const float* cb = (const float*)d_in[1];
    float* out = (float*)d_out;

    float*  t   = (float*)d_ws;
    float*  ps  = (float*)((char*)d_ws + 16777216);
    double* cbn = (double*)((char*)d_ws + 16793600);

    kc_prep<<<N_TOK, 256, 0, stream>>>(x, t, ps);
    kc_cbn<<<(R_STAGES * H_HEADS * K_CODES) / 4, 256, 0, stream>>>(cb, cbn);

    const int stage_lds = 79360;
    for (int r = 0; r < R_STAGES; ++r) {
        kc_stage<<<H_HEADS * (N_TOK / TN), 256, stage_lds, stream>>>(cb, cbn, t, r);
    }
    kc_out<<<N_TOK, 256, 0, stream>>>(x, t, ps, out);
}

// Round 2
// 3019.537 us; speedup vs baseline: 2.9855x; 2.9855x over previous
//
#include <hip/hip_runtime.h>

#define R_STAGES 8
#define H_HEADS  8
#define K_CODES  4096
#define C_DIM    128
#define N_TOK    4096      // B*S
#define FEAT     1024      // H*C
#define HKC      (H_HEADS * K_CODES * C_DIM)   // 4,194,304 elems per stage

#define CAP      24
#define MARGIN   5e-3f

typedef _Float16 half8  __attribute__((ext_vector_type(8)));
typedef _Float16 half4v __attribute__((ext_vector_type(4)));
typedef float    f32x4  __attribute__((ext_vector_type(4)));

#define MFMA16(A, B, C) __builtin_amdgcn_mfma_f32_16x16x32_f16((A), (B), (C), 0, 0, 0)

// ---------------------------------------------------------------------------
// ws layout (bytes):
//   t    : float    [H][N][C]   @ 0            (16,777,216)
//   ps   : float    [N]         @ 16,777,216   (16,384)
//   cn   : float    [R][H][K]   @ 16,793,600   (1,048,576)
//   cb16 : _Float16 [...]       @ 17,842,176   (67,108,864 full / 8,388,608 per-stage)
// ---------------------------------------------------------------------------

__global__ void kc_prep(const float* __restrict__ x, float* __restrict__ t,
                        float* __restrict__ ps) {
    int n = blockIdx.x;
    const float* xr = x + (size_t)n * FEAT;

    double ss = 0.0;
    for (int i = threadIdx.x; i < FEAT; i += 256) {
        float v = xr[i];
        ss += (double)v * (double)v;
    }
    for (int off = 32; off > 0; off >>= 1) ss += __shfl_down(ss, off);

    __shared__ double sred[4];
    __shared__ float s_p;
    int wid = threadIdx.x >> 6, lane = threadIdx.x & 63;
    if (lane == 0) sred[wid] = ss;
    __syncthreads();
    if (threadIdx.x == 0) {
        double tot = sred[0] + sred[1] + sred[2] + sred[3];
        float p = (float)sqrt(tot);
        ps[n] = p;
        s_p = p;
    }
    __syncthreads();
    float p = s_p;

    for (int i = threadIdx.x; i < FEAT; i += 256) {
        int c = i & 127;
        float v = xr[(i & ~127) + ((c & 1) << 6) + (c >> 1)];
        size_t o = ((size_t)(i >> 7) * N_TOK + n) * C_DIM + c;
        t[o] = v / p;
    }
}

// cn[r,h,k] = sum_c cb^2 (fp64 accumulate, stored fp32 for screening only)
__global__ void kc_cbn(const float* __restrict__ cb, float* __restrict__ cn) {
    int w = (blockIdx.x << 2) + (threadIdx.x >> 6);
    int lane = threadIdx.x & 63;
    const float* row = cb + (size_t)w * C_DIM;
    float a = row[lane], b = row[lane + 64];
    double s = (double)a * a + (double)b * b;
    for (int off = 32; off > 0; off >>= 1) s += __shfl_down(s, off);
    if (lane == 0) cn[w] = (float)s;
}

// fp32 -> fp16 conversion, 4 elements/thread
__global__ void kc_cvt(const float* __restrict__ s, _Float16* __restrict__ d, int n4) {
    int i = blockIdx.x * 256 + threadIdx.x;
    if (i < n4) {
        f32x4 v = ((const f32x4*)s)[i];
        half4v o;
        o[0] = (_Float16)v[0]; o[1] = (_Float16)v[1];
        o[2] = (_Float16)v[2]; o[3] = (_Float16)v[3];
        ((half4v*)d)[i] = o;
    }
}

// One residual stage. Pointers pre-offset to stage r.
// Block: one head, 64 tokens (4 waves x 16 tokens). Screen all K codes via
// fp16 MFMA, collect candidates within MARGIN of running per-lane min,
// fp64-rescore candidates, update t -= cb[winner] in fp32.
__global__ __launch_bounds__(256)
void kc_stage(const float* __restrict__ cb32, const _Float16* __restrict__ cb16,
              const float* __restrict__ cn, float* __restrict__ t) {
    __shared__ int    lists[256 * CAP];
    __shared__ int    cnts[256];
    __shared__ int    tokOver[64];
    __shared__ int    winner[64];
    __shared__ double redD[256];
    __shared__ int    redI[256];

    const int tid  = threadIdx.x;
    const int h    = blockIdx.x >> 6;
    const int n0   = (blockIdx.x & 63) * 64;
    const int w    = tid >> 6;
    const int lane = tid & 63;
    const int col  = lane & 15;   // token col (D layout), also code row base within tile
    const int kb   = lane >> 4;   // k-block for operands; row group for D

    const _Float16* cbh16 = cb16 + (size_t)h * K_CODES * C_DIM;
    const float*    cbh32 = cb32 + (size_t)h * K_CODES * C_DIM;
    const float*    cnh   = cn   + (size_t)h * K_CODES;
    float* th = t + ((size_t)h * N_TOK + n0) * C_DIM;

    if (tid < 64) tokOver[tid] = 0;

    // loop-invariant t fragments (B operand): token = w*16+col, k = kb*8 + j*32 + i
    const int tokl = (w << 4) + col;
    const float* trow = th + (size_t)tokl * C_DIM;
    half8 tf[4];
#pragma unroll
    for (int j = 0; j < 4; ++j) {
        const float* p = trow + j * 32 + kb * 8;
        f32x4 lo = *(const f32x4*)(p);
        f32x4 hi = *(const f32x4*)(p + 4);
        half8 v;
        v[0] = (_Float16)lo[0]; v[1] = (_Float16)lo[1];
        v[2] = (_Float16)lo[2]; v[3] = (_Float16)lo[3];
        v[4] = (_Float16)hi[0]; v[5] = (_Float16)hi[1];
        v[6] = (_Float16)hi[2]; v[7] = (_Float16)hi[3];
        tf[j] = v;
    }

    int   cnt  = 0;
    bool  over = false;
    float rb   = 3.4e38f;

    const _Float16* cb_lane = cbh16 + (size_t)col * C_DIM + kb * 8;

    auto load_tiles = [&](int kt, half8* A, half8* B, f32x4& c0, f32x4& c1) {
        const _Float16* p0 = cb_lane + (size_t)kt * C_DIM;
        const _Float16* p1 = p0 + 16 * C_DIM;
#pragma unroll
        for (int j = 0; j < 4; ++j) {
            A[j] = *(const half8*)(p0 + j * 32);
            B[j] = *(const half8*)(p1 + j * 32);
        }
        c0 = *(const f32x4*)(cnh + kt + kb * 4);
        c1 = *(const f32x4*)(cnh + kt + 16 + kb * 4);
    };

    auto epilogue = [&](int kt, const f32x4& acc, const f32x4& cv) {
#pragma unroll
        for (int rr = 0; rr < 4; ++rr) {
            float d = cv[rr] - 2.0f * acc[rr];
            if (d < rb + MARGIN) {
                int k = kt + (kb << 2) + rr;
                if (cnt < CAP) lists[tid * CAP + cnt] = k; else over = true;
                ++cnt;
                if (d < rb) rb = d;
            }
        }
    };

    auto compute = [&](int kt, const half8* A, const half8* B,
                       const f32x4& c0, const f32x4& c1) {
        f32x4 a0 = {0.f, 0.f, 0.f, 0.f}, a1 = {0.f, 0.f, 0.f, 0.f};
        a0 = MFMA16(A[0], tf[0], a0);  a1 = MFMA16(B[0], tf[0], a1);
        a0 = MFMA16(A[1], tf[1], a0);  a1 = MFMA16(B[1], tf[1], a1);
        a0 = MFMA16(A[2], tf[2], a0);  a1 = MFMA16(B[2], tf[2], a1);
        a0 = MFMA16(A[3], tf[3], a0);  a1 = MFMA16(B[3], tf[3], a1);
        epilogue(kt, a0, c0);
        epilogue(kt + 16, a1, c1);
    };

    half8 xA[4], xB[4], yA[4], yB[4];
    f32x4 xc0, xc1, yc0, yc1;
    load_tiles(0, xA, xB, xc0, xc1);
    for (int k0 = 0; k0 < K_CODES; k0 += 64) {
        load_tiles(k0 + 32, yA, yB, yc0, yc1);
        compute(k0, xA, xB, xc0, xc1);
        if (k0 + 64 < K_CODES) load_tiles(k0 + 64, xA, xB, xc0, xc1);
        compute(k0 + 32, yA, yB, yc0, yc1);
    }

    cnts[tid] = (cnt < CAP) ? cnt : CAP;
    if (over) atomicOr(&tokOver[tokl], 1);
    __syncthreads();

    // ---- exact fp64 rescoring of collected candidates (4 threads/token) ----
    {
        const int tok  = tid >> 2;
        const int q    = tid & 3;
        const int slot = ((tok >> 4) << 6) + (q << 4) + (tok & 15);
        const int m    = cnts[slot];
        const float* trw = th + (size_t)tok * C_DIM;
        double bd = 1e300; int bi = 0x7fffffff;
        for (int e = 0; e < m; ++e) {
            const int k = lists[slot * CAP + e];
            const float* crow = cbh32 + (size_t)k * C_DIM;
            double dot = 0.0, cx = 0.0;
            for (int c = 0; c < C_DIM; ++c) {
                double cvv = (double)crow[c];
                double tvv = (double)trw[c];
                cx  = fma(cvv, cvv, cx);
                dot = fma(tvv, cvv, dot);
            }
            double d = cx - 2.0 * dot;
            if (d < bd || (d == bd && k < bi)) { bd = d; bi = k; }
        }
        redD[tid] = bd; redI[tid] = bi;
    }
    __syncthreads();
    if ((tid & 3) == 0) {
        const int tok = tid >> 2;
        double bd = redD[tid]; int bi = redI[tid];
#pragma unroll
        for (int q = 1; q < 4; ++q) {
            double d = redD[tid + q]; int i2 = redI[tid + q];
            if (d < bd || (d == bd && i2 < bi)) { bd = d; bi = i2; }
        }
        winner[tok] = bi;
    }
    __syncthreads();

    // ---- rare fallback: full fp64 scan for list-overflow tokens ----
    for (int ot = 0; ot < 64; ++ot) {
        if (!tokOver[ot]) continue;       // uniform (LDS) -> no divergence hazard
        const float* trw = th + (size_t)ot * C_DIM;
        double bd = 1e300; int bi = 0x7fffffff;
        for (int k = tid; k < K_CODES; k += 256) {
            const float* crow = cbh32 + (size_t)k * C_DIM;
            double dot = 0.0, cx = 0.0;
            for (int c = 0; c < C_DIM; ++c) {
                double cvv = (double)crow[c];
                double tvv = (double)trw[c];
                cx  = fma(cvv, cvv, cx);
                dot = fma(tvv, cvv, dot);
            }
            double d = cx - 2.0 * dot;
            if (d < bd || (d == bd && k < bi)) { bd = d; bi = k; }
        }
        for (int off = 32; off > 0; off >>= 1) {
            double od = __shfl_down(bd, off);
            int    oi = __shfl_down(bi, off);
            if (od < bd || (od == bd && oi < bi)) { bd = od; bi = oi; }
        }
        if (lane == 0) { redD[w] = bd; redI[w] = bi; }
        __syncthreads();
        if (tid == 0) {
            double b2 = redD[0]; int i2 = redI[0];
            for (int q = 1; q < 4; ++q) {
                if (redD[q] < b2 || (redD[q] == b2 && redI[q] < i2)) {
                    b2 = redD[q]; i2 = redI[q];
                }
            }
            winner[ot] = i2;
        }
        __syncthreads();
    }

    // ---- residual update: t -= cb[winner], fp32 (matches reference) ----
    for (int i = tid; i < 64 * C_DIM; i += 256) {
        const int tok = i >> 7, c = i & 127;
        const float qv = cbh32[(size_t)winner[tok] * C_DIM + c];
        th[(size_t)tok * C_DIM + c] -= qv;
    }
}

__global__ void kc_out(const float* __restrict__ x, const float* __restrict__ t,
                       const float* __restrict__ ps, float* __restrict__ out) {
    int n = blockIdx.x;
    float p = ps[n];
    const float* xr = x + (size_t)n * FEAT;
    for (int i = threadIdx.x; i < FEAT; i += 256) {
        int c = i & 127;
        float v = xr[(i & ~127) + ((c & 1) << 6) + (c >> 1)];
        float t0 = v / p;
        float tf = t[((size_t)(i >> 7) * N_TOK + n) * C_DIM + c];
        out[(size_t)n * FEAT + i] = (t0 - tf) * p;
    }
}

extern "C" void kernel_launch(void* const* d_in, const int* in_sizes, int n_in,
                              void* d_out, int out_size, void* d_ws, size_t ws_size,
                              hipStream_t stream) {
    const float* x  = (const float*)d_in[0];
    const float* cb = (const float*)d_in[1];
    float* out = (float*)d_out;

    float*    t    = (float*)d_ws;
    float*    ps   = (float*)((char*)d_ws + 16777216);
    float*    cn   = (float*)((char*)d_ws + 16793600);
    _Float16* cb16 = (_Float16*)((char*)d_ws + 17842176);

    const bool full = (ws_size >= 84951040ull);   // room for all-stage fp16 codebook

    kc_prep<<<N_TOK, 256, 0, stream>>>(x, t, ps);
    kc_cbn<<<(R_STAGES * H_HEADS * K_CODES) / 4, 256, 0, stream>>>(cb, cn);
    if (full) {
        const int n4 = R_STAGES * HKC / 4;
        kc_cvt<<<(n4 + 255) / 256, 256, 0, stream>>>(cb, cb16, n4);
    }

    for (int r = 0; r < R_STAGES; ++r) {
        const _Float16* cb16s;
        if (full) {
            cb16s = cb16 + (size_t)r * HKC;
        } else {
            const int n4 = HKC / 4;
            kc_cvt<<<(n4 + 255) / 256, 256, 0, stream>>>(cb + (size_t)r * HKC, cb16, n4);
            cb16s = cb16;
        }
        kc_stage<<<H_HEADS * (N_TOK / 64), 256, 0, stream>>>(
            cb + (size_t)r * HKC, cb16s,
            cn + (size_t)r * H_HEADS * K_CODES, t);
    }
    kc_out<<<N_TOK, 256, 0, stream>>>(x, t, ps, out);
}

// Round 3
// 1223.227 us; speedup vs baseline: 7.3697x; 2.4685x over previous
//
#include <hip/hip_runtime.h>

#define R_STAGES 8
#define H_HEADS  8
#define K_CODES  4096
#define C_DIM    128
#define N_TOK    4096      // B*S
#define FEAT     1024      // H*C
#define HKC      (H_HEADS * K_CODES * C_DIM)   // elems per stage

#define MARGIN   1e-2f
#define PCAP     16

typedef _Float16 half8  __attribute__((ext_vector_type(8)));
typedef _Float16 half4v __attribute__((ext_vector_type(4)));
typedef float    f32x4  __attribute__((ext_vector_type(4)));

#define MFMA16(A, B, C) __builtin_amdgcn_mfma_f32_16x16x32_f16((A), (B), (C), 0, 0, 0)

// ---------------------------------------------------------------------------
// ws layout (bytes):
//   t    : float    [H][N][C]   @ 0            (16,777,216)
//   ps   : float    [N]         @ 16,777,216   (16,384)
//   cn   : float    [R][H][K]   @ 16,793,600   (1,048,576)
//   cb16 : _Float16             @ 17,842,176   (33,554,432 full / 8,388,608 per-stage)
// ---------------------------------------------------------------------------

__global__ void kc_prep(const float* __restrict__ x, float* __restrict__ t,
                        float* __restrict__ ps) {
    int n = blockIdx.x;
    const float* xr = x + (size_t)n * FEAT;

    double ss = 0.0;
    for (int i = threadIdx.x; i < FEAT; i += 256) {
        float v = xr[i];
        ss += (double)v * (double)v;
    }
    for (int off = 32; off > 0; off >>= 1) ss += __shfl_down(ss, off);

    __shared__ double sred[4];
    __shared__ float s_p;
    int wid = threadIdx.x >> 6, lane = threadIdx.x & 63;
    if (lane == 0) sred[wid] = ss;
    __syncthreads();
    if (threadIdx.x == 0) {
        double tot = sred[0] + sred[1] + sred[2] + sred[3];
        float p = (float)sqrt(tot);
        ps[n] = p;
        s_p = p;
    }
    __syncthreads();
    float p = s_p;

    for (int i = threadIdx.x; i < FEAT; i += 256) {
        int c = i & 127;
        float v = xr[(i & ~127) + ((c & 1) << 6) + (c >> 1)];
        size_t o = ((size_t)(i >> 7) * N_TOK + n) * C_DIM + c;
        t[o] = v / p;
    }
}

__global__ void kc_cbn(const float* __restrict__ cb, float* __restrict__ cn) {
    int w = (blockIdx.x << 2) + (threadIdx.x >> 6);
    int lane = threadIdx.x & 63;
    const float* row = cb + (size_t)w * C_DIM;
    float a = row[lane], b = row[lane + 64];
    double s = (double)a * a + (double)b * b;
    for (int off = 32; off > 0; off >>= 1) s += __shfl_down(s, off);
    if (lane == 0) cn[w] = (float)s;
}

__global__ void kc_cvt(const float* __restrict__ s, _Float16* __restrict__ d, int n4) {
    int i = blockIdx.x * 256 + threadIdx.x;
    if (i < n4) {
        f32x4 v = ((const f32x4*)s)[i];
        half4v o;
        o[0] = (_Float16)v[0]; o[1] = (_Float16)v[1];
        o[2] = (_Float16)v[2]; o[3] = (_Float16)v[3];
        ((half4v*)d)[i] = o;
    }
}

// One residual stage. Block = (head, 64 tokens); 4 waves split K into quarters.
// Each wave screens 64 tokens x 1024 codes via fp16 MFMA (phase 1: min only),
// cross-wave reduce -> per-token screened min, phase 2 rescan collects codes
// within MARGIN of the min, fp64 rescore picks the exact argmin.
__global__ __launch_bounds__(256, 2)
void kc_stage(const float* __restrict__ cb32, const _Float16* __restrict__ cb16,
              const float* __restrict__ cn, float* __restrict__ t) {
    __shared__ float  rbs[256][4];
    __shared__ float  mtok[64];
    __shared__ int    pcnt[64];
    __shared__ int    plist[64][PCAP];
    __shared__ int    winner[64];
    __shared__ double redD[256];
    __shared__ int    redI[256];

    const int tid  = threadIdx.x;
    const int w    = tid >> 6;
    const int lane = tid & 63;
    const int col  = lane & 15;      // token within group / A row within tile
    const int rblk = lane >> 4;      // k-slice block for operands; D row block
    const int h    = blockIdx.x & 7;             // XCD swizzle: head == bid%8
    const int n0   = (blockIdx.x >> 3) << 6;

    const _Float16* cbh16 = cb16 + (size_t)h * K_CODES * C_DIM;
    const float*    cbh32 = cb32 + (size_t)h * K_CODES * C_DIM;
    const float*    cnh   = cn   + (size_t)h * K_CODES;
    float* th = t + ((size_t)h * N_TOK + n0) * C_DIM;

    if (tid < 64) pcnt[tid] = 0;

    // loop-invariant token fragments: tf[g][j] = B[k=rblk*8+j*32 .. +8][tok g*16+col]
    half8 tf[4][4];
#pragma unroll
    for (int g = 0; g < 4; ++g) {
        const float* trow = th + (size_t)(g * 16 + col) * C_DIM;
#pragma unroll
        for (int j = 0; j < 4; ++j) {
            const float* p = trow + j * 32 + rblk * 8;
            f32x4 lo = *(const f32x4*)p;
            f32x4 hi = *(const f32x4*)(p + 4);
            half8 v;
            v[0] = (_Float16)lo[0]; v[1] = (_Float16)lo[1];
            v[2] = (_Float16)lo[2]; v[3] = (_Float16)lo[3];
            v[4] = (_Float16)hi[0]; v[5] = (_Float16)hi[1];
            v[6] = (_Float16)hi[2]; v[7] = (_Float16)hi[3];
            tf[g][j] = v;
        }
    }

    const int kbase = w << 10;                   // this wave's K-quarter
    const _Float16* cbA = cbh16 + (size_t)(kbase + col) * C_DIM + rblk * 8;
    const float*    cnA = cnh + kbase + (rblk << 2);

    auto loadA = [&](int it, half8* A, f32x4& cv) {
        const _Float16* p = cbA + (size_t)it * (16 * C_DIM);
#pragma unroll
        for (int j = 0; j < 4; ++j) A[j] = *(const half8*)(p + j * 32);
        cv = *(const f32x4*)(cnA + it * 16);
    };

    float rb0 = 3.4e38f, rb1 = 3.4e38f, rb2 = 3.4e38f, rb3 = 3.4e38f;

    auto screen = [&](const half8* A, const f32x4& cv) {
        f32x4 a0 = {0.f,0.f,0.f,0.f}, a1 = {0.f,0.f,0.f,0.f};
        f32x4 a2 = {0.f,0.f,0.f,0.f}, a3 = {0.f,0.f,0.f,0.f};
#pragma unroll
        for (int j = 0; j < 4; ++j) {
            a0 = MFMA16(A[j], tf[0][j], a0);
            a1 = MFMA16(A[j], tf[1][j], a1);
            a2 = MFMA16(A[j], tf[2][j], a2);
            a3 = MFMA16(A[j], tf[3][j], a3);
        }
        {
            float d0 = cv[0] - 2.f*a0[0], d1 = cv[1] - 2.f*a0[1];
            float d2 = cv[2] - 2.f*a0[2], d3 = cv[3] - 2.f*a0[3];
            rb0 = fminf(rb0, fminf(fminf(d0, d1), fminf(d2, d3)));
        }
        {
            float d0 = cv[0] - 2.f*a1[0], d1 = cv[1] - 2.f*a1[1];
            float d2 = cv[2] - 2.f*a1[2], d3 = cv[3] - 2.f*a1[3];
            rb1 = fminf(rb1, fminf(fminf(d0, d1), fminf(d2, d3)));
        }
        {
            float d0 = cv[0] - 2.f*a2[0], d1 = cv[1] - 2.f*a2[1];
            float d2 = cv[2] - 2.f*a2[2], d3 = cv[3] - 2.f*a2[3];
            rb2 = fminf(rb2, fminf(fminf(d0, d1), fminf(d2, d3)));
        }
        {
            float d0 = cv[0] - 2.f*a3[0], d1 = cv[1] - 2.f*a3[1];
            float d2 = cv[2] - 2.f*a3[2], d3 = cv[3] - 2.f*a3[3];
            rb3 = fminf(rb3, fminf(fminf(d0, d1), fminf(d2, d3)));
        }
    };

    {   // ---- phase 1: min-only screen, double-buffered ----
        half8 X[4], Y[4]; f32x4 cx, cy;
        loadA(0, X, cx);
#pragma unroll 1
        for (int it = 0; it < 64; it += 2) {
            loadA(it + 1, Y, cy);
            screen(X, cx);
            if (it + 2 < 64) loadA(it + 2, X, cx);
            screen(Y, cy);
        }
    }

    rbs[tid][0] = rb0; rbs[tid][1] = rb1; rbs[tid][2] = rb2; rbs[tid][3] = rb3;
    __syncthreads();
    if (tid < 64) {
        int g = tid >> 4, c2 = tid & 15;
        float m = 3.4e38f;
#pragma unroll
        for (int ww = 0; ww < 4; ++ww)
#pragma unroll
            for (int rr = 0; rr < 4; ++rr)
                m = fminf(m, rbs[ww * 64 + rr * 16 + c2][g]);
        mtok[tid] = m;
    }
    __syncthreads();

    const float thr0 = mtok[col]      + MARGIN;
    const float thr1 = mtok[16 + col] + MARGIN;
    const float thr2 = mtok[32 + col] + MARGIN;
    const float thr3 = mtok[48 + col] + MARGIN;

    auto collect = [&](const half8* A, const f32x4& cv, int it) {
        f32x4 a0 = {0.f,0.f,0.f,0.f}, a1 = {0.f,0.f,0.f,0.f};
        f32x4 a2 = {0.f,0.f,0.f,0.f}, a3 = {0.f,0.f,0.f,0.f};
#pragma unroll
        for (int j = 0; j < 4; ++j) {
            a0 = MFMA16(A[j], tf[0][j], a0);
            a1 = MFMA16(A[j], tf[1][j], a1);
            a2 = MFMA16(A[j], tf[2][j], a2);
            a3 = MFMA16(A[j], tf[3][j], a3);
        }
        const int kb2 = kbase + it * 16 + (rblk << 2);
#pragma unroll
        for (int rr = 0; rr < 4; ++rr) {
            float d0 = cv[rr] - 2.f * a0[rr];
            float d1 = cv[rr] - 2.f * a1[rr];
            float d2 = cv[rr] - 2.f * a2[rr];
            float d3 = cv[rr] - 2.f * a3[rr];
            if (d0 < thr0) { int idx = atomicAdd(&pcnt[col],      1); if (idx < PCAP) plist[col][idx]      = kb2 + rr; }
            if (d1 < thr1) { int idx = atomicAdd(&pcnt[16 + col], 1); if (idx < PCAP) plist[16 + col][idx] = kb2 + rr; }
            if (d2 < thr2) { int idx = atomicAdd(&pcnt[32 + col], 1); if (idx < PCAP) plist[32 + col][idx] = kb2 + rr; }
            if (d3 < thr3) { int idx = atomicAdd(&pcnt[48 + col], 1); if (idx < PCAP) plist[48 + col][idx] = kb2 + rr; }
        }
    };

    {   // ---- phase 2: rescan, collect near-min candidates ----
        half8 X[4], Y[4]; f32x4 cx, cy;
        loadA(0, X, cx);
#pragma unroll 1
        for (int it = 0; it < 64; it += 2) {
            loadA(it + 1, Y, cy);
            collect(X, cx, it);
            if (it + 2 < 64) loadA(it + 2, X, cx);
            collect(Y, cy, it + 1);
        }
    }
    __syncthreads();

    // ---- exact fp64 rescore of candidates (4 threads/token) ----
    {
        const int tok = tid >> 2, q = tid & 3;
        int m = pcnt[tok]; if (m > PCAP) m = PCAP;
        const float* trw = th + (size_t)tok * C_DIM;
        double bd = 1e300; int bi = 0x7fffffff;
        for (int e = q; e < m; e += 4) {
            const int k = plist[tok][e];
            const float* crow = cbh32 + (size_t)k * C_DIM;
            double dot = 0.0, cx2 = 0.0;
            for (int c = 0; c < C_DIM; ++c) {
                double cvv = (double)crow[c];
                double tvv = (double)trw[c];
                cx2 = fma(cvv, cvv, cx2);
                dot = fma(tvv, cvv, dot);
            }
            double d = cx2 - 2.0 * dot;
            if (d < bd || (d == bd && k < bi)) { bd = d; bi = k; }
        }
        redD[tid] = bd; redI[tid] = bi;
    }
    __syncthreads();
    if ((tid & 3) == 0) {
        const int tok = tid >> 2;
        double bd = redD[tid]; int bi = redI[tid];
#pragma unroll
        for (int q = 1; q < 4; ++q) {
            double d = redD[tid + q]; int i2 = redI[tid + q];
            if (d < bd || (d == bd && i2 < bi)) { bd = d; bi = i2; }
        }
        winner[tok] = bi;
    }
    __syncthreads();

    // ---- rare fallback: full fp64 scan for overflowed tokens ----
    for (int ot = 0; ot < 64; ++ot) {
        if (pcnt[ot] <= PCAP) continue;     // uniform LDS value -> no divergence
        const float* trw = th + (size_t)ot * C_DIM;
        double bd = 1e300; int bi = 0x7fffffff;
        for (int k = tid; k < K_CODES; k += 256) {
            const float* crow = cbh32 + (size_t)k * C_DIM;
            double dot = 0.0, cx2 = 0.0;
            for (int c = 0; c < C_DIM; ++c) {
                double cvv = (double)crow[c];
                double tvv = (double)trw[c];
                cx2 = fma(cvv, cvv, cx2);
                dot = fma(tvv, cvv, dot);
            }
            double d = cx2 - 2.0 * dot;
            if (d < bd || (d == bd && k < bi)) { bd = d; bi = k; }
        }
        for (int off = 32; off > 0; off >>= 1) {
            double od = __shfl_down(bd, off);
            int    oi = __shfl_down(bi, off);
            if (od < bd || (od == bd && oi < bi)) { bd = od; bi = oi; }
        }
        if (lane == 0) { redD[w] = bd; redI[w] = bi; }
        __syncthreads();
        if (tid == 0) {
            double b2 = redD[0]; int i2 = redI[0];
            for (int q = 1; q < 4; ++q) {
                if (redD[q] < b2 || (redD[q] == b2 && redI[q] < i2)) {
                    b2 = redD[q]; i2 = redI[q];
                }
            }
            winner[ot] = i2;
        }
        __syncthreads();
    }

    // ---- residual update: t -= cb[winner] (fp32, matches reference) ----
    for (int i = tid; i < 64 * C_DIM; i += 256) {
        const int tok = i >> 7, c = i & 127;
        const float qv = cbh32[(size_t)winner[tok] * C_DIM + c];
        th[(size_t)tok * C_DIM + c] -= qv;
    }
}

__global__ void kc_out(const float* __restrict__ x, const float* __restrict__ t,
                       const float* __restrict__ ps, float* __restrict__ out) {
    int n = blockIdx.x;
    float p = ps[n];
    const float* xr = x + (size_t)n * FEAT;
    for (int i = threadIdx.x; i < FEAT; i += 256) {
        int c = i & 127;
        float v = xr[(i & ~127) + ((c & 1) << 6) + (c >> 1)];
        float t0 = v / p;
        float tf = t[((size_t)(i >> 7) * N_TOK + n) * C_DIM + c];
        out[(size_t)n * FEAT + i] = (t0 - tf) * p;
    }
}

extern "C" void kernel_launch(void* const* d_in, const int* in_sizes, int n_in,
                              void* d_out, int out_size, void* d_ws, size_t ws_size,
                              hipStream_t stream) {
    const float* x  = (const float*)d_in[0];
    const float* cb = (const float*)d_in[1];
    float* out = (float*)d_out;

    float*    t    = (float*)d_ws;
    float*    ps   = (float*)((char*)d_ws + 16777216);
    float*    cn   = (float*)((char*)d_ws + 16793600);
    _Float16* cb16 = (_Float16*)((char*)d_ws + 17842176);

    const bool full = (ws_size >= 51500000ull);

    kc_prep<<<N_TOK, 256, 0, stream>>>(x, t, ps);
    kc_cbn<<<(R_STAGES * H_HEADS * K_CODES) / 4, 256, 0, stream>>>(cb, cn);
    if (full) {
        const int n4 = R_STAGES * HKC / 4;
        kc_cvt<<<(n4 + 255) / 256, 256, 0, stream>>>(cb, cb16, n4);
    }

    for (int r = 0; r < R_STAGES; ++r) {
        const _Float16* cb16s;
        if (full) {
            cb16s = cb16 + (size_t)r * HKC;
        } else {
            const int n4 = HKC / 4;
            kc_cvt<<<(n4 + 255) / 256, 256, 0, stream>>>(cb + (size_t)r * HKC, cb16, n4);
            cb16s = cb16;
        }
        kc_stage<<<H_HEADS * (N_TOK / 64), 256, 0, stream>>>(
            cb + (size_t)r * HKC, cb16s,
            cn + (size_t)r * H_HEADS * K_CODES, t);
    }
    kc_out<<<N_TOK, 256, 0, stream>>>(x, t, ps, out);
}

// Round 4
// 1062.677 us; speedup vs baseline: 8.4832x; 1.1511x over previous
//
#include <hip/hip_runtime.h>

#define R_STAGES 8
#define H_HEADS  8
#define K_CODES  4096
#define C_DIM    128
#define N_TOK    4096      // B*S
#define FEAT     1024      // H*C
#define HKC      (H_HEADS * K_CODES * C_DIM)   // elems per stage

#define MARGIN   1.2e-2f
#define WCAP     512
#define TMS      260       // tmin row stride in fp16 elems (520 B, 8-aligned, bank-safe)

typedef _Float16 half8  __attribute__((ext_vector_type(8)));
typedef _Float16 half4v __attribute__((ext_vector_type(4)));
typedef float    f32x4  __attribute__((ext_vector_type(4)));

#define MFMA16(A, B, C) __builtin_amdgcn_mfma_f32_16x16x32_f16((A), (B), (C), 0, 0, 0)

// ---------------------------------------------------------------------------
// ws layout (bytes):
//   t    : float    [H][N][C]   @ 0            (16,777,216)
//   ps   : float    [N]         @ 16,777,216   (16,384)
//   cn   : float    [R][H][K]   @ 16,793,600   (1,048,576)
//   cb16 : _Float16             @ 17,842,176   (67,108,864 full / 8,388,608 per-stage)
//   full path needs 84,951,040 B total.
// ---------------------------------------------------------------------------

__global__ void kc_prep(const float* __restrict__ x, float* __restrict__ t,
                        float* __restrict__ ps) {
    int n = blockIdx.x;
    const float* xr = x + (size_t)n * FEAT;

    double ss = 0.0;
    for (int i = threadIdx.x; i < FEAT; i += 256) {
        float v = xr[i];
        ss += (double)v * (double)v;
    }
    for (int off = 32; off > 0; off >>= 1) ss += __shfl_down(ss, off);

    __shared__ double sred[4];
    __shared__ float s_p;
    int wid = threadIdx.x >> 6, lane = threadIdx.x & 63;
    if (lane == 0) sred[wid] = ss;
    __syncthreads();
    if (threadIdx.x == 0) {
        double tot = sred[0] + sred[1] + sred[2] + sred[3];
        float p = (float)sqrt(tot);
        ps[n] = p;
        s_p = p;
    }
    __syncthreads();
    float p = s_p;

    for (int i = threadIdx.x; i < FEAT; i += 256) {
        int c = i & 127;
        float v = xr[(i & ~127) + ((c & 1) << 6) + (c >> 1)];
        size_t o = ((size_t)(i >> 7) * N_TOK + n) * C_DIM + c;
        t[o] = v / p;
    }
}

// Fused fp32->fp16 convert + squared-norm (one pass over cb). One wave/row.
__global__ void kc_cvtn(const float* __restrict__ cb, _Float16* __restrict__ cb16,
                        float* __restrict__ cn) {
    int w = (blockIdx.x << 2) + (threadIdx.x >> 6);
    int lane = threadIdx.x & 63;
    const float* row = cb + (size_t)w * C_DIM;
    float a = row[lane], b = row[lane + 64];
    _Float16* dr = cb16 + (size_t)w * C_DIM;
    dr[lane]      = (_Float16)a;
    dr[lane + 64] = (_Float16)b;
    double s = (double)a * a + (double)b * b;
    for (int off = 32; off > 0; off >>= 1) s += __shfl_down(s, off);
    if (lane == 0) cn[w] = (float)s;
}

// ---------------------------------------------------------------------------
// One residual stage for one (head, 64-token) block.
// Single fp16-MFMA scan writes per-(token, 16-code-tile) mins to LDS; flagged
// tiles (within MARGIN of the token min) get exact fp64 rescoring.
// ---------------------------------------------------------------------------
__device__ __forceinline__ void stage_body(
    const float* __restrict__ cbh32, const _Float16* __restrict__ cbh16,
    const float* __restrict__ cnh, float* __restrict__ th) {

    __shared__ _Float16 tmin[64 * TMS];   // [tok][tile] fp16 tile-mins
    __shared__ float    rbs[256][4];
    __shared__ float    mtok[64];
    __shared__ int      wl[WCAP];
    __shared__ double   eD[WCAP];
    __shared__ int      eI[WCAP];
    __shared__ int      winner[64];
    __shared__ int      wlCnt;

    const int tid  = threadIdx.x;
    const int w    = tid >> 6;
    const int lane = tid & 63;
    const int col  = lane & 15;
    const int rblk = lane >> 4;

    if (tid == 0) wlCnt = 0;

    // loop-invariant token fragments: tf[g][j] = t[tok=g*16+col][k=rblk*8+j*32 ..+8]
    half8 tf[4][4];
#pragma unroll
    for (int g = 0; g < 4; ++g) {
        const float* trow = th + (size_t)(g * 16 + col) * C_DIM;
#pragma unroll
        for (int j = 0; j < 4; ++j) {
            const float* p = trow + j * 32 + rblk * 8;
            f32x4 lo = *(const f32x4*)p;
            f32x4 hi = *(const f32x4*)(p + 4);
            half8 v;
            v[0] = (_Float16)lo[0]; v[1] = (_Float16)lo[1];
            v[2] = (_Float16)lo[2]; v[3] = (_Float16)lo[3];
            v[4] = (_Float16)hi[0]; v[5] = (_Float16)hi[1];
            v[6] = (_Float16)hi[2]; v[7] = (_Float16)hi[3];
            tf[g][j] = v;
        }
    }

    const int kbase = w << 10;                    // wave's K-quarter
    const _Float16* cbA = cbh16 + (size_t)(kbase + col) * C_DIM + rblk * 8;
    const float*    cnA = cnh + kbase + (rblk << 2);

    auto loadA = [&](int it, half8* A, f32x4& cv) {
        const _Float16* p = cbA + (size_t)it * (16 * C_DIM);
#pragma unroll
        for (int j = 0; j < 4; ++j) A[j] = *(const half8*)(p + j * 32);
        cv = *(const f32x4*)(cnA + it * 16);
    };

    float rbg0 = 3.4e38f, rbg1 = 3.4e38f, rbg2 = 3.4e38f, rbg3 = 3.4e38f;

    auto screen = [&](const half8* A, const f32x4& cv, int wtile) {
        f32x4 a0 = {0.f,0.f,0.f,0.f}, a1 = {0.f,0.f,0.f,0.f};
        f32x4 a2 = {0.f,0.f,0.f,0.f}, a3 = {0.f,0.f,0.f,0.f};
#pragma unroll
        for (int j = 0; j < 4; ++j) {
            a0 = MFMA16(A[j], tf[0][j], a0);
            a1 = MFMA16(A[j], tf[1][j], a1);
            a2 = MFMA16(A[j], tf[2][j], a2);
            a3 = MFMA16(A[j], tf[3][j], a3);
        }
        float m0 = fminf(fminf(cv[0] - 2.f*a0[0], cv[1] - 2.f*a0[1]),
                         fminf(cv[2] - 2.f*a0[2], cv[3] - 2.f*a0[3]));
        float m1 = fminf(fminf(cv[0] - 2.f*a1[0], cv[1] - 2.f*a1[1]),
                         fminf(cv[2] - 2.f*a1[2], cv[3] - 2.f*a1[3]));
        float m2 = fminf(fminf(cv[0] - 2.f*a2[0], cv[1] - 2.f*a2[1]),
                         fminf(cv[2] - 2.f*a2[2], cv[3] - 2.f*a2[3]));
        float m3 = fminf(fminf(cv[0] - 2.f*a3[0], cv[1] - 2.f*a3[1]),
                         fminf(cv[2] - 2.f*a3[2], cv[3] - 2.f*a3[3]));
        // tile min across the 4 rblk lane-groups (16 codes total)
        m0 = fminf(m0, __shfl_xor(m0, 16)); m0 = fminf(m0, __shfl_xor(m0, 32));
        m1 = fminf(m1, __shfl_xor(m1, 16)); m1 = fminf(m1, __shfl_xor(m1, 32));
        m2 = fminf(m2, __shfl_xor(m2, 16)); m2 = fminf(m2, __shfl_xor(m2, 32));
        m3 = fminf(m3, __shfl_xor(m3, 16)); m3 = fminf(m3, __shfl_xor(m3, 32));
        rbg0 = fminf(rbg0, m0); rbg1 = fminf(rbg1, m1);
        rbg2 = fminf(rbg2, m2); rbg3 = fminf(rbg3, m3);
        if (rblk == 0) {
            tmin[(col)      * TMS + wtile] = (_Float16)m0;
            tmin[(16 + col) * TMS + wtile] = (_Float16)m1;
            tmin[(32 + col) * TMS + wtile] = (_Float16)m2;
            tmin[(48 + col) * TMS + wtile] = (_Float16)m3;
        }
    };

    // ---- phase 1: single scan, depth-4 register ring prefetch ----
    {
        half8 A0[4], A1[4], A2[4], A3[4];
        f32x4 v0, v1, v2, v3;
        loadA(0, A0, v0); loadA(1, A1, v1); loadA(2, A2, v2); loadA(3, A3, v3);
        const int wbase = w << 6;
#pragma unroll 1
        for (int j = 0; j < 16; ++j) {
            const int b4 = j << 2;
            screen(A0, v0, wbase + b4);
            if (j < 15) loadA(b4 + 4, A0, v0);
            screen(A1, v1, wbase + b4 + 1);
            if (j < 15) loadA(b4 + 5, A1, v1);
            screen(A2, v2, wbase + b4 + 2);
            if (j < 15) loadA(b4 + 6, A2, v2);
            screen(A3, v3, wbase + b4 + 3);
            if (j < 15) loadA(b4 + 7, A3, v3);
        }
    }
    rbs[tid][0] = rbg0; rbs[tid][1] = rbg1; rbs[tid][2] = rbg2; rbs[tid][3] = rbg3;
    __syncthreads();

    // ---- per-token screened min (from per-lane running mins) ----
    if (tid < 64) {
        const int g = tid >> 4, c2 = tid & 15;
        float m = 3.4e38f;
#pragma unroll
        for (int ww = 0; ww < 4; ++ww) m = fminf(m, rbs[ww * 64 + c2][g]);
        mtok[tid] = m;
    }
    __syncthreads();

    // ---- build worklist of flagged (token, tile) pairs ----
    {
        const int tok = tid >> 2, q = tid & 3;
        const float thr = mtok[tok] + MARGIN;
        const half4v* rowp = (const half4v*)(tmin + tok * TMS + (q << 6));
#pragma unroll 4
        for (int j4 = 0; j4 < 16; ++j4) {
            half4v v = rowp[j4];
#pragma unroll
            for (int e = 0; e < 4; ++e) {
                if ((float)v[e] < thr) {
                    int idx = atomicAdd(&wlCnt, 1);
                    if (idx < WCAP) wl[idx] = (tok << 8) | ((q << 6) + (j4 << 2) + e);
                }
            }
        }
    }
    __syncthreads();

    int E = wlCnt;
    if (E <= WCAP) {
        // ---- fp64 rescore: one 16-lane group per flagged tile ----
        for (int e0 = 0; e0 < E; e0 += 16) {
            const int e = e0 + (tid >> 4);
            double bd = 1e300; int bi = 0x7fffffff;
            if (e < E) {
                const int meta = wl[e];
                const int tok = meta >> 8;
                const int k = ((meta & 255) << 4) + (tid & 15);
                const float* crow = cbh32 + (size_t)k * C_DIM;
                const float* trw  = th + (size_t)tok * C_DIM;
                double cx0=0,cx1=0,cx2=0,cx3=0,d0=0,d1=0,d2=0,d3=0;
#pragma unroll 4
                for (int c = 0; c < C_DIM; c += 4) {
                    double cv0 = crow[c],   tv0 = trw[c];
                    double cv1 = crow[c+1], tv1 = trw[c+1];
                    double cv2 = crow[c+2], tv2 = trw[c+2];
                    double cv3 = crow[c+3], tv3 = trw[c+3];
                    cx0 = fma(cv0,cv0,cx0); d0 = fma(tv0,cv0,d0);
                    cx1 = fma(cv1,cv1,cx1); d1 = fma(tv1,cv1,d1);
                    cx2 = fma(cv2,cv2,cx2); d2 = fma(tv2,cv2,d2);
                    cx3 = fma(cv3,cv3,cx3); d3 = fma(tv3,cv3,d3);
                }
                bd = ((cx0+cx1)+(cx2+cx3)) - 2.0*((d0+d1)+(d2+d3));
                bi = k;
            }
#pragma unroll
            for (int off = 1; off < 16; off <<= 1) {
                double od = __shfl_xor(bd, off);
                int    oi = __shfl_xor(bi, off);
                if (od < bd || (od == bd && oi < bi)) { bd = od; bi = oi; }
            }
            if ((tid & 15) == 0 && e < E) { eD[e >> 0] = bd; eI[e] = bi; }
        }
        __syncthreads();
        // per-token combine over entries
        if (tid < 64) {
            double bd = 1e300; int bi = 0x7fffffff;
            for (int e = 0; e < E; ++e) {
                if ((wl[e] >> 8) == tid) {
                    double d = eD[e]; int i2 = eI[e];
                    if (d < bd || (d == bd && i2 < bi)) { bd = d; bi = i2; }
                }
            }
            winner[tid] = bi;
        }
        __syncthreads();
    } else {
        // ---- overflow fallback (probability ~0): full fp64 scan, all tokens ----
        for (int ot = 0; ot < 64; ++ot) {
            const float* trw = th + (size_t)ot * C_DIM;
            double bd = 1e300; int bi = 0x7fffffff;
            for (int k = tid; k < K_CODES; k += 256) {
                const float* crow = cbh32 + (size_t)k * C_DIM;
                double cx0=0,cx1=0,cx2=0,cx3=0,d0=0,d1=0,d2=0,d3=0;
                for (int c = 0; c < C_DIM; c += 4) {
                    double cv0 = crow[c],   tv0 = trw[c];
                    double cv1 = crow[c+1], tv1 = trw[c+1];
                    double cv2 = crow[c+2], tv2 = trw[c+2];
                    double cv3 = crow[c+3], tv3 = trw[c+3];
                    cx0 = fma(cv0,cv0,cx0); d0 = fma(tv0,cv0,d0);
                    cx1 = fma(cv1,cv1,cx1); d1 = fma(tv1,cv1,d1);
                    cx2 = fma(cv2,cv2,cx2); d2 = fma(tv2,cv2,d2);
                    cx3 = fma(cv3,cv3,cx3); d3 = fma(tv3,cv3,d3);
                }
                double d = ((cx0+cx1)+(cx2+cx3)) - 2.0*((d0+d1)+(d2+d3));
                if (d < bd || (d == bd && k < bi)) { bd = d; bi = k; }
            }
            for (int off = 1; off <= 32; off <<= 1) {
                double od = __shfl_xor(bd, off);
                int    oi = __shfl_xor(bi, off);
                if (od < bd || (od == bd && oi < bi)) { bd = od; bi = oi; }
            }
            if (lane == 0) { eD[w] = bd; eI[w] = bi; }
            __syncthreads();
            if (tid == 0) {
                double b2 = eD[0]; int i2 = eI[0];
                for (int q = 1; q < 4; ++q) {
                    if (eD[q] < b2 || (eD[q] == b2 && eI[q] < i2)) { b2 = eD[q]; i2 = eI[q]; }
                }
                winner[ot] = i2;
            }
            __syncthreads();
        }
    }

    // ---- residual update: t -= cb[winner] (fp32, matches reference) ----
    for (int i = tid; i < 64 * C_DIM; i += 256) {
        const int tok = i >> 7, c = i & 127;
        th[(size_t)tok * C_DIM + c] -= cbh32[(size_t)winner[tok] * C_DIM + c];
    }
    __syncthreads();
}

// All 8 stages in one kernel — residual chain is per-token independent.
__global__ __launch_bounds__(256, 2)
void kc_all(const float* __restrict__ cb32, const _Float16* __restrict__ cb16,
            const float* __restrict__ cn, float* __restrict__ t) {
    const int h  = blockIdx.x & 7;               // XCD-affine head mapping
    const int n0 = (blockIdx.x >> 3) << 6;
    float* th = t + ((size_t)h * N_TOK + n0) * C_DIM;
#pragma unroll 1
    for (int r = 0; r < R_STAGES; ++r) {
        const size_t off = (size_t)(r * H_HEADS + h) * K_CODES;
        stage_body(cb32 + off * C_DIM, cb16 + off * C_DIM, cn + off, th);
    }
}

// Single-stage variant (used when ws can't hold the full fp16 codebook).
__global__ __launch_bounds__(256, 2)
void kc_stage_one(const float* __restrict__ cb32, const _Float16* __restrict__ cb16,
                  const float* __restrict__ cn, float* __restrict__ t) {
    const int h  = blockIdx.x & 7;
    const int n0 = (blockIdx.x >> 3) << 6;
    float* th = t + ((size_t)h * N_TOK + n0) * C_DIM;
    const size_t off = (size_t)h * K_CODES;
    stage_body(cb32 + off * C_DIM, cb16 + off * C_DIM, cn + off, th);
}

__global__ void kc_out(const float* __restrict__ x, const float* __restrict__ t,
                       const float* __restrict__ ps, float* __restrict__ out) {
    int n = blockIdx.x;
    float p = ps[n];
    const float* xr = x + (size_t)n * FEAT;
    for (int i = threadIdx.x; i < FEAT; i += 256) {
        int c = i & 127;
        float v = xr[(i & ~127) + ((c & 1) << 6) + (c >> 1)];
        float t0 = v / p;
        float tf = t[((size_t)(i >> 7) * N_TOK + n) * C_DIM + c];
        out[(size_t)n * FEAT + i] = (t0 - tf) * p;
    }
}

extern "C" void kernel_launch(void* const* d_in, const int* in_sizes, int n_in,
                              void* d_out, int out_size, void* d_ws, size_t ws_size,
                              hipStream_t stream) {
    const float* x  = (const float*)d_in[0];
    const float* cb = (const float*)d_in[1];
    float* out = (float*)d_out;

    float*    t    = (float*)d_ws;
    float*    ps   = (float*)((char*)d_ws + 16777216);
    float*    cn   = (float*)((char*)d_ws + 16793600);
    _Float16* cb16 = (_Float16*)((char*)d_ws + 17842176);

    const bool full = (ws_size >= 84951040ull);   // 17,842,176 + 67,108,864

    kc_prep<<<N_TOK, 256, 0, stream>>>(x, t, ps);

    if (full) {
        kc_cvtn<<<(R_STAGES * H_HEADS * K_CODES) / 4, 256, 0, stream>>>(cb, cb16, cn);
        kc_all<<<H_HEADS * (N_TOK / 64), 256, 0, stream>>>(cb, cb16, cn, t);
    } else {
        for (int r = 0; r < R_STAGES; ++r) {
            kc_cvtn<<<(H_HEADS * K_CODES) / 4, 256, 0, stream>>>(
                cb + (size_t)r * HKC, cb16, cn + (size_t)r * H_HEADS * K_CODES);
            kc_stage_one<<<H_HEADS * (N_TOK / 64), 256, 0, stream>>>(
                cb + (size_t)r * HKC, cb16, cn + (size_t)r * H_HEADS * K_CODES, t);
        }
    }

    kc_out<<<N_TOK, 256, 0, stream>>>(x, t, ps, out);
}